// Round 3
// baseline (1625.694 us; speedup 1.0000x reference)
//
#include <hip/hip_runtime.h>

typedef _Float16 v8h  __attribute__((ext_vector_type(8)));
typedef _Float16 v4h  __attribute__((ext_vector_type(4)));
typedef float    v4f  __attribute__((ext_vector_type(4)));
typedef unsigned int u32x4 __attribute__((ext_vector_type(4)));

#define BATCH   128
#define TSTEPS  256
#define DFEAT   256
#define UDIM    1024
#define NCOL    2048
#define ASTRIDE 1288   // LDS A stride (halfs): 1280 K + 8 pad

// 128 blocks x 1024 threads. Each block owns TWO row-groups (gA=gp, gB=gp+4;
// 16 batch rows each) and one 32-column U-slice (cb = blockIdx>>2).
// The two groups are software-pipelined: group X's h exchange
// (store -> flag -> peer poll -> load, ~2-3 IC RTTs) hides under group Y's
// MFMA+EW phase. Exchange protocol is IDENTICAL to the proven single-group
// kernel: sc0+sc1 ops, tagged flags (value t+1 published at step t),
// parity-double-buffered fp16 hbufs. Dependency DAG: phase(g,t) waits only on
// peers' phase(g,t-1) -> acyclic -> no deadlock given co-residency (128 blocks
// on 256 CUs, 1 block/CU).
//
// Per-phase schedule:
//   poll flags(g) >= t; stage h(t) -> Alds; barrier
//   MFMA (dual acc chains) -> Plds; barrier
//   reduce + elementwise (waves 0..3) -> Hout, h_reg; barrier
//   wave0: pack h(t+1) -> hbuf store (sc0 sc1) -> vmcnt(0) -> flag := t+1
//   out stores; x(t+1)/dt(t+1) prefetch (drain during next phase)

__global__ __launch_bounds__(1024, 4)
void ltc_rnn_kernel(const float* __restrict__ features,  // [128,256,256]
                    const float* __restrict__ tsteps,    // [128,256]
                    const float* __restrict__ Wx,        // [256,2048]
                    const float* __restrict__ Wh,        // [1024,2048]
                    const float* __restrict__ bias,      // [2048]
                    const float* __restrict__ wtau,      // [1024]
                    const float* __restrict__ h0,        // [128,1024]
                    float* __restrict__ out,             // [128,256,1024]
                    unsigned* __restrict__ flags,        // [8][64] u32 (tagged t+1)
                    _Float16* __restrict__ hbufs)        // 2 x [128,1024] fp16
{
  __shared__ _Float16 AldsA[16 * ASTRIDE];
  __shared__ _Float16 AldsB[16 * ASTRIDE];
  __shared__ float    Plds[16 * 64 * 4];
  __shared__ _Float16 Hout[16][32];
  __shared__ float    dtA[2][16];
  __shared__ float    dtB[2][16];

  const int tid  = threadIdx.x;
  const int w    = tid >> 6;
  const int lane = tid & 63;
  const int n    = lane & 15;
  const int q    = lane >> 4;
  const int cg   = w & 3;
  const int ks   = w >> 2;
  const int gp   = blockIdx.x & 3;     // pair id: groups gp and gp+4
  const int cb   = blockIdx.x >> 2;    // 0..31
  const int u0   = cb * 32;
  const int gA   = gp;
  const int gB   = gp + 4;

  // ---- wave-stationary weights: fp32 -> fp16 VGPRs, once (group-independent) ----
  const int gcol = (n < 8) ? (u0 + cg * 8 + n) : (UDIM + u0 + cg * 8 + (n - 8));
  v8h bfr[10];
  #pragma unroll
  for (int c = 0; c < 10; ++c) {
    #pragma unroll
    for (int j = 0; j < 8; ++j) {
      const int k = ks * 320 + c * 32 + q * 8 + j;
      const float wv = (k < DFEAT) ? Wx[(size_t)k * NCOL + gcol]
                                   : Wh[(size_t)(k - DFEAT) * NCOL + gcol];
      bfr[c][j] = (_Float16)wv;
    }
  }

  const float bias_own = bias[gcol];
  const int   u_lane   = u0 + cg * 8 + (n & 7);
  const float tau      = logf(1.0f + __expf(wtau[u_lane]));

  float h_regA[4], h_regB[4];
  #pragma unroll
  for (int i = 0; i < 4; ++i) {
    h_regA[i] = h0[(size_t)(gA * 16 + q * 4 + i) * UDIM + u_lane];
    h_regB[i] = h0[(size_t)(gB * 16 + q * 4 + i) * UDIM + u_lane];
  }

  // ---- pre-loop staging: x(0), dt(0), h0 for both groups ----
  auto prestage = [&](const int g, _Float16* __restrict__ Ald, float (&dtl)[2][16]) {
    if (tid < 16) dtl[0][tid] = tsteps[(size_t)(g * 16 + tid) * TSTEPS + 0];
    const int r = tid >> 6, k4 = tid & 63;
    v4f x4 = *(const v4f*)(features + (size_t)(g * 16 + r) * (TSTEPS * DFEAT) + k4 * 4);
    v4h xh = {(_Float16)x4.x, (_Float16)x4.y, (_Float16)x4.z, (_Float16)x4.w};
    *(v4h*)&Ald[r * ASTRIDE + k4 * 4] = xh;
    #pragma unroll
    for (int jj = 0; jj < 4; ++jj) {
      const int c = tid + jj * 1024, hr = c >> 8, hk4 = c & 255;
      v4f h4 = *(const v4f*)(h0 + (size_t)(g * 16 + hr) * UDIM + hk4 * 4);
      v4h hh = {(_Float16)h4.x, (_Float16)h4.y, (_Float16)h4.z, (_Float16)h4.w};
      *(v4h*)&Ald[hr * ASTRIDE + DFEAT + hk4 * 4] = hh;
    }
  };
  prestage(gA, AldsA, dtA);
  prestage(gB, AldsB, dtB);
  __syncthreads();

  // ---- one group-phase of one time step ----
  auto phase = [&](const int g, _Float16* __restrict__ Ald,
                   float (&hreg)[4], float (&dtl)[2][16], const int t) {
    // poll peers' flags (>= t) and stage h(t); all waves independently
    if (t > 0) {
      const unsigned* fp = &flags[g * 64 + (lane & 31)];
      const unsigned  tg = (unsigned)(t - 1);          // stale if flag <= t-1
      for (;;) {
        unsigned v;
        asm volatile("global_load_dword %0, %1, off sc0 sc1\n\t"
                     "s_waitcnt vmcnt(0)"
                     : "=v"(v) : "v"(fp) : "memory");
        if (__ballot(v <= tg) == 0ull) break;
      }
      const _Float16* hsrc = hbufs + ((size_t)(t & 1)) * (BATCH * UDIM);
      const int c0 = tid, c1 = tid + 1024;
      const _Float16* p0 = hsrc + (size_t)(g * 16 + (c0 >> 7)) * UDIM + (c0 & 127) * 8;
      const _Float16* p1 = hsrc + (size_t)(g * 16 + (c1 >> 7)) * UDIM + (c1 & 127) * 8;
      u32x4 r0, r1;
      asm volatile("global_load_dwordx4 %0, %2, off sc0 sc1\n\t"
                   "global_load_dwordx4 %1, %3, off sc0 sc1\n\t"
                   "s_waitcnt vmcnt(0)"
                   : "=v"(r0), "=v"(r1) : "v"(p0), "v"(p1) : "memory");
      *(v8h*)&Ald[(c0 >> 7) * ASTRIDE + DFEAT + (c0 & 127) * 8] = __builtin_bit_cast(v8h, r0);
      *(v8h*)&Ald[(c1 >> 7) * ASTRIDE + DFEAT + (c1 & 127) * 8] = __builtin_bit_cast(v8h, r1);
    }
    __syncthreads();                                   // Sa: A(t) tile ready

    // MFMA: 16 rows x 16 cols x K-slice 320, dual accumulator chains
    {
      v4f acc0 = {0.f, 0.f, 0.f, 0.f};
      v4f acc1 = {0.f, 0.f, 0.f, 0.f};
      const _Float16* abase = &Ald[n * ASTRIDE + ks * 320 + q * 8];
      #pragma unroll
      for (int c = 0; c < 10; c += 2) {
        v8h a0 = *(const v8h*)(abase + c * 32);
        v8h a1 = *(const v8h*)(abase + (c + 1) * 32);
        acc0 = __builtin_amdgcn_mfma_f32_16x16x32_f16(a0, bfr[c],     acc0, 0, 0, 0);
        acc1 = __builtin_amdgcn_mfma_f32_16x16x32_f16(a1, bfr[c + 1], acc1, 0, 0, 0);
      }
      v4f acc = acc0 + acc1;
      *(v4f*)&Plds[(w * 64 + lane) * 4] = acc;
    }
    __syncthreads();                                   // S1: Plds ready

    // reduce + elementwise (waves 0..3); h tile -> Hout, out vals -> regs
    float outv[4];
    if (w < 4) {
      v4f p = *(v4f*)&Plds[((0 * 4 + w) * 64 + lane) * 4];
      #pragma unroll
      for (int s = 1; s < 4; ++s) {
        v4f ps = *(v4f*)&Plds[((s * 4 + w) * 64 + lane) * 4];
        p.x += ps.x; p.y += ps.y; p.z += ps.z; p.w += ps.w;
      }
      float pf[4], pa[4];
      #pragma unroll
      for (int i = 0; i < 4; ++i) {
        const float v = p[i] + bias_own;
        const float o = __shfl_xor(v, 8);
        pf[i] = v; pa[i] = o;
      }
      if (n < 8) {
        #pragma unroll
        for (int i = 0; i < 4; ++i) {
          const int   row_l = q * 4 + i;
          const float dt    = dtl[t & 1][row_l];
          const float f     = 1.0f / (1.0f + __expf(-pf[i]));
          const float av    = 2.0f / (1.0f + __expf(-2.0f * pa[i])) - 1.0f;
          const float decay = __expf(-dt * (tau + f));
          const float hn    = (hreg[i] - av) * decay + av;
          hreg[i] = hn;
          outv[i] = hn;
          Hout[row_l][w * 8 + n] = (_Float16)hn;
        }
      }
    }
    __syncthreads();                                   // S2: Hout ready

    const bool more = (t + 1 < TSTEPS);

    // wave0: packed h-store (sc0 sc1), ack, publish tagged flag
    if (w == 0 && more) {
      const int row = lane >> 2, c8 = lane & 3;
      v8h hv = *(v8h*)&Hout[row][c8 * 8];
      _Float16* dp = hbufs + ((size_t)((t + 1) & 1)) * (BATCH * UDIM)
                   + (size_t)(g * 16 + row) * UDIM + u0 + c8 * 8;
      asm volatile("global_store_dwordx4 %0, %1, off sc0 sc1\n\t"
                   "s_waitcnt vmcnt(0)"
                   :: "v"(dp), "v"(__builtin_bit_cast(u32x4, hv)) : "memory");
      if (lane == 0) {
        unsigned tg = (unsigned)(t + 1);
        asm volatile("global_store_dword %0, %1, off sc0 sc1"
                     :: "v"(&flags[g * 64 + cb]), "v"(tg) : "memory");
      }
    }

    // off-critical-path: out stores + x(t+1)/dt(t+1) prefetch (drain during next phase)
    if (w < 4 && n < 8) {
      #pragma unroll
      for (int i = 0; i < 4; ++i) {
        const int row = g * 16 + q * 4 + i;
        out[(size_t)row * (TSTEPS * UDIM) + (size_t)t * UDIM + u_lane] = outv[i];
      }
    }
    if (more) {
      if (tid < 16) dtl[(t + 1) & 1][tid] = tsteps[(size_t)(g * 16 + tid) * TSTEPS + t + 1];
      const int r = tid >> 6, k4 = tid & 63;
      v4f x4 = *(const v4f*)(features + (size_t)(g * 16 + r) * (TSTEPS * DFEAT)
                             + (size_t)(t + 1) * DFEAT + k4 * 4);
      v4h xh = {(_Float16)x4.x, (_Float16)x4.y, (_Float16)x4.z, (_Float16)x4.w};
      *(v4h*)&Ald[r * ASTRIDE + k4 * 4] = xh;
    }
  };

  for (int t = 0; t < TSTEPS; ++t) {
    phase(gA, AldsA, h_regA, dtA, t);   // A's exchange hid under previous B-phase
    phase(gB, AldsB, h_regB, dtB, t);   // B's exchange hides under next A-phase
  }
}

extern "C" void kernel_launch(void* const* d_in, const int* in_sizes, int n_in,
                              void* d_out, int out_size, void* d_ws, size_t ws_size,
                              hipStream_t stream) {
  const float* features = (const float*)d_in[0];
  const float* tsamp    = (const float*)d_in[1];
  const float* Wx       = (const float*)d_in[2];
  const float* Wh       = (const float*)d_in[3];
  const float* bias     = (const float*)d_in[4];
  const float* wtau     = (const float*)d_in[5];
  const float* h0       = (const float*)d_in[6];
  float*     out    = (float*)d_out;
  unsigned*  flags  = (unsigned*)d_ws;
  _Float16*  hbufs  = (_Float16*)((char*)d_ws + 4096);

  hipMemsetAsync(d_ws, 0, 4096, stream);   // zero flags (ws is poisoned)
  hipLaunchKernelGGL(ltc_rnn_kernel, dim3(128), dim3(1024), 0, stream,
                     features, tsamp, Wx, Wh, bias, wtau, h0, out, flags, hbufs);
}

// Round 4
// 1026.020 us; speedup vs baseline: 1.5845x; 1.5845x over previous
//
#include <hip/hip_runtime.h>

typedef _Float16 v8h  __attribute__((ext_vector_type(8)));
typedef _Float16 v4h  __attribute__((ext_vector_type(4)));
typedef float    v4f  __attribute__((ext_vector_type(4)));
typedef unsigned int u32x4 __attribute__((ext_vector_type(4)));

#define BATCH   128
#define TSTEPS  256
#define DFEAT   256
#define UDIM    1024
#define NCOL    2048
#define ASTRIDE 1288   // LDS A stride (halfs)

// 256 blocks x 1024 threads. g = blockIdx%8 (row group of 16 batch rows),
// cb = blockIdx/8 (32 col-blocks). Wave w: cg=w&3 (16-col tile), ks=w>>2 (K-slice 320).
// Inter-block exchange: h tile via sc0/sc1 (IC-coherent) + per-block tagged flags.
// (Protocol byte-identical to the proven 925us kernel.)
// Scheduling changes vs proven baseline:
//   - no poll barrier: all 16 waves poll the 32-flag line; each thread stages its
//     h chunk right after its wave's poll succeeds (S4 orders LDS writes vs MFMA)
//   - early flag probe issued before out-stores/prefetch, checked after one
//     vmcnt(0) drain (reg-tied asm so the check can't be hoisted)
//   - dual MFMA accumulator chains (halved dependent-latency chain)

__global__ __launch_bounds__(1024)
void ltc_rnn_kernel(const float* __restrict__ features,  // [128,256,256]
                    const float* __restrict__ tsteps,    // [128,256]
                    const float* __restrict__ Wx,        // [256,2048]
                    const float* __restrict__ Wh,        // [1024,2048]
                    const float* __restrict__ bias,      // [2048]
                    const float* __restrict__ wtau,      // [1024]
                    const float* __restrict__ h0,        // [128,1024]
                    float* __restrict__ out,             // [128,256,1024]
                    unsigned* __restrict__ flags,        // [8][64] u32 (tagged t+1)
                    _Float16* __restrict__ hbufs)        // 2 x [128,1024] fp16
{
  __shared__ _Float16 Alds[16 * ASTRIDE];
  __shared__ float    Plds[16 * 64 * 4];
  __shared__ _Float16 Hout[16][32];
  __shared__ float    dtlds[2][16];

  const int tid  = threadIdx.x;
  const int w    = tid >> 6;
  const int lane = tid & 63;
  const int n    = lane & 15;
  const int q    = lane >> 4;
  const int cg   = w & 3;
  const int ks   = w >> 2;
  const int g    = blockIdx.x & 7;
  const int cb   = blockIdx.x >> 3;
  const int u0   = cb * 32;

  // ---- wave-stationary weights: fp32 -> fp16 VGPRs, once ----
  const int gcol = (n < 8) ? (u0 + cg * 8 + n) : (UDIM + u0 + cg * 8 + (n - 8));
  v8h bfr[10];
  #pragma unroll
  for (int c = 0; c < 10; ++c) {
    #pragma unroll
    for (int j = 0; j < 8; ++j) {
      const int k = ks * 320 + c * 32 + q * 8 + j;
      const float wv = (k < DFEAT) ? Wx[(size_t)k * NCOL + gcol]
                                   : Wh[(size_t)(k - DFEAT) * NCOL + gcol];
      bfr[c][j] = (_Float16)wv;
    }
  }

  const float bias_own = bias[gcol];
  const int   u_lane   = u0 + cg * 8 + (n & 7);
  const float tau      = logf(1.0f + __expf(wtau[u_lane]));

  float h_reg[4];
  #pragma unroll
  for (int i = 0; i < 4; ++i)
    h_reg[i] = h0[(size_t)(g * 16 + q * 4 + i) * UDIM + u_lane];

  // ---- pre-loop staging: x(0), dt(0), h0 ----
  if (tid < 16) dtlds[0][tid] = tsteps[(size_t)(g * 16 + tid) * TSTEPS + 0];
  {
    const int r = tid >> 6, k4 = tid & 63;
    v4f x4 = *(const v4f*)(features + (size_t)(g * 16 + r) * (TSTEPS * DFEAT) + k4 * 4);
    v4h xh = {(_Float16)x4.x, (_Float16)x4.y, (_Float16)x4.z, (_Float16)x4.w};
    *(v4h*)&Alds[r * ASTRIDE + k4 * 4] = xh;
    #pragma unroll
    for (int jj = 0; jj < 4; ++jj) {
      const int c = tid + jj * 1024, hr = c >> 8, hk4 = c & 255;
      v4f h4 = *(const v4f*)(h0 + (size_t)(g * 16 + hr) * UDIM + hk4 * 4);
      v4h hh = {(_Float16)h4.x, (_Float16)h4.y, (_Float16)h4.z, (_Float16)h4.w};
      *(v4h*)&Alds[hr * ASTRIDE + DFEAT + hk4 * 4] = hh;
    }
  }
  __syncthreads();

  for (int t = 0; t < TSTEPS; ++t) {
    const bool more = (t + 1 < TSTEPS);
    _Float16* hdst = hbufs + ((t + 1) & 1) * (BATCH * UDIM);

    // ---- MFMA: 16 rows x 16 cols x K-slice 320, dual accumulator chains ----
    {
      v4f acc0 = {0.f, 0.f, 0.f, 0.f};
      v4f acc1 = {0.f, 0.f, 0.f, 0.f};
      const _Float16* abase = &Alds[n * ASTRIDE + ks * 320 + q * 8];
      #pragma unroll
      for (int c = 0; c < 10; c += 2) {
        v8h a0 = *(const v8h*)(abase + c * 32);
        v8h a1 = *(const v8h*)(abase + (c + 1) * 32);
        acc0 = __builtin_amdgcn_mfma_f32_16x16x32_f16(a0, bfr[c],     acc0, 0, 0, 0);
        acc1 = __builtin_amdgcn_mfma_f32_16x16x32_f16(a1, bfr[c + 1], acc1, 0, 0, 0);
      }
      v4f acc = acc0 + acc1;
      *(v4f*)&Plds[(w * 64 + lane) * 4] = acc;
    }
    __syncthreads();                                   // S1: Plds ready

    // ---- reduce + elementwise (waves 0..3); h tile -> LDS, out vals -> regs ----
    float outv[4];
    if (w < 4) {
      v4f p = *(v4f*)&Plds[((0 * 4 + w) * 64 + lane) * 4];
      #pragma unroll
      for (int s = 1; s < 4; ++s) {
        v4f ps = *(v4f*)&Plds[((s * 4 + w) * 64 + lane) * 4];
        p.x += ps.x; p.y += ps.y; p.z += ps.z; p.w += ps.w;
      }
      float pf[4], pa[4];
      #pragma unroll
      for (int i = 0; i < 4; ++i) {
        const float v = p[i] + bias_own;
        const float o = __shfl_xor(v, 8);
        pf[i] = v; pa[i] = o;
      }
      if (n < 8) {
        #pragma unroll
        for (int i = 0; i < 4; ++i) {
          const int   row_l = q * 4 + i;
          const float dt    = dtlds[t & 1][row_l];
          const float f     = 1.0f / (1.0f + __expf(-pf[i]));
          const float av    = 2.0f / (1.0f + __expf(-2.0f * pa[i])) - 1.0f;
          const float decay = __expf(-dt * (tau + f));
          const float hn    = (h_reg[i] - av) * decay + av;
          h_reg[i] = hn;
          outv[i]  = hn;
          Hout[row_l][w * 8 + n] = (_Float16)hn;
        }
      }
    }
    __syncthreads();                                   // S2: Hout ready

    // ---- wave0: packed h-store to IC, ack, publish tagged flag ----
    if (w == 0 && more) {
      const int row = lane >> 2, c8 = lane & 3;
      v8h hv = *(v8h*)&Hout[row][c8 * 8];
      _Float16* dp = hdst + (size_t)(g * 16 + row) * UDIM + u0 + c8 * 8;
      asm volatile("global_store_dwordx4 %0, %1, off sc0 sc1\n\t"
                   "s_waitcnt vmcnt(0)"
                   :: "v"(dp), "v"(__builtin_bit_cast(u32x4, hv)) : "memory");
      if (lane == 0) {
        unsigned tg = (unsigned)(t + 1);
        asm volatile("global_store_dword %0, %1, off sc0 sc1"
                     :: "v"(&flags[g * 64 + cb]), "v"(tg) : "memory");
      }
    }

    // ---- early flag probe (non-blocking), then off-critical-path work ----
    const unsigned* fp = &flags[g * 64 + (lane & 31)];
    unsigned v0 = 0;
    if (more) {
      asm volatile("global_load_dword %0, %1, off sc0 sc1"
                   : "=v"(v0) : "v"(fp) : "memory");
    }

    if (w < 4 && n < 8) {
      #pragma unroll
      for (int i = 0; i < 4; ++i) {
        const int row = g * 16 + q * 4 + i;
        out[(size_t)row * (TSTEPS * UDIM) + (size_t)t * UDIM + u_lane] = outv[i];
      }
    }
    if (more) {
      if (tid < 16) dtlds[(t + 1) & 1][tid] = tsteps[(size_t)(g * 16 + tid) * TSTEPS + t + 1];
      const int r = tid >> 6, k4 = tid & 63;
      v4f x4 = *(const v4f*)(features + (size_t)(g * 16 + r) * (TSTEPS * DFEAT)
                             + (size_t)(t + 1) * DFEAT + k4 * 4);
      v4h xh = {(_Float16)x4.x, (_Float16)x4.y, (_Float16)x4.z, (_Float16)x4.w};
      *(v4h*)&Alds[r * ASTRIDE + k4 * 4] = xh;
    }

    // ---- all waves: check probe, spin only if stale; then stage h(t+1) ----
    if (more) {
      const unsigned tg = (unsigned)t;                 // stale if flag <= t
      asm volatile("s_waitcnt vmcnt(0)" : "+v"(v0) :: "memory");  // reg-tied drain
      if (__ballot(v0 <= tg) != 0ull) {
        for (;;) {
          unsigned v;
          asm volatile("global_load_dword %0, %1, off sc0 sc1\n\t"
                       "s_waitcnt vmcnt(0)"
                       : "=v"(v) : "v"(fp) : "memory");
          if (__ballot(v <= tg) == 0ull) break;
        }
      }
      // per-thread h staging (no barrier between poll and load)
      const _Float16* hsrc = hbufs + ((t + 1) & 1) * (BATCH * UDIM);
      const int c0 = tid, c1 = tid + 1024;
      const _Float16* p0 = hsrc + (size_t)(g * 16 + (c0 >> 7)) * UDIM + (c0 & 127) * 8;
      const _Float16* p1 = hsrc + (size_t)(g * 16 + (c1 >> 7)) * UDIM + (c1 & 127) * 8;
      u32x4 r0, r1;
      asm volatile("global_load_dwordx4 %0, %2, off sc0 sc1\n\t"
                   "global_load_dwordx4 %1, %3, off sc0 sc1\n\t"
                   "s_waitcnt vmcnt(0)"
                   : "=v"(r0), "=v"(r1) : "v"(p0), "v"(p1) : "memory");
      *(v8h*)&Alds[(c0 >> 7) * ASTRIDE + DFEAT + (c0 & 127) * 8] = __builtin_bit_cast(v8h, r0);
      *(v8h*)&Alds[(c1 >> 7) * ASTRIDE + DFEAT + (c1 & 127) * 8] = __builtin_bit_cast(v8h, r1);
      __syncthreads();                                 // S4: A(t+1) ready
    }
  }
}

extern "C" void kernel_launch(void* const* d_in, const int* in_sizes, int n_in,
                              void* d_out, int out_size, void* d_ws, size_t ws_size,
                              hipStream_t stream) {
  const float* features = (const float*)d_in[0];
  const float* tsamp    = (const float*)d_in[1];
  const float* Wx       = (const float*)d_in[2];
  const float* Wh       = (const float*)d_in[3];
  const float* bias     = (const float*)d_in[4];
  const float* wtau     = (const float*)d_in[5];
  const float* h0       = (const float*)d_in[6];
  float*     out    = (float*)d_out;
  unsigned*  flags  = (unsigned*)d_ws;
  _Float16*  hbufs  = (_Float16*)((char*)d_ws + 4096);

  hipMemsetAsync(d_ws, 0, 4096, stream);   // zero flags (ws is poisoned)
  hipLaunchKernelGGL(ltc_rnn_kernel, dim3(256), dim3(1024), 0, stream,
                     features, tsamp, Wx, Wh, bias, wtau, h0, out, flags, hbufs);
}